// Round 8
// baseline (706.676 us; speedup 1.0000x reference)
//
#include <hip/hip_runtime.h>

#define N_Q   65536
#define N_C   2048
#define KNN_K 16
#define CDIM  64
#define SLCAP 128
#define KINF  0x7FFFFFFF
#define WSZ   108544  // halves per weight image

#define GN     16     // grid cells per axis
#define GCELLS 4096
#define LCAP   448    // per-cell candidate-list capacity (u16), 7 slots/lane
#define NSLOT  7

typedef _Float16 half_t;
typedef float v4f __attribute__((ext_vector_type(4)));
typedef half_t v8h __attribute__((ext_vector_type(8)));

#define ASTRIDE 136   // 128 + 8 pad (halves); row = 272 B = 17*16 B
#define DSTRIDE 40    // 32 + 8 pad

// ---------------------------------------------------------------------------
// DPP lane-xor (wm tree reduction).
// ---------------------------------------------------------------------------
__device__ __forceinline__ int dppx(int v, int j){
  if (j == 1) return __builtin_amdgcn_mov_dpp(v, 0xB1,  0xF, 0xF, true);
  if (j == 2) return __builtin_amdgcn_mov_dpp(v, 0x4E,  0xF, 0xF, true);
  if (j == 8) return __builtin_amdgcn_mov_dpp(v, 0x128, 0xF, 0xF, true);
  return __shfl_xor(v, j, 64);
}
__device__ __forceinline__ float dppxf(float v, int j){
  return __int_as_float(dppx(__float_as_int(v), j));
}

// Exact 16th-smallest via bitwise binary search over [0x40800000,0x40FFFFFF]
// (s = d^2+4 in [4,8) -> fixed exponent; 23 mantissa rounds).
__device__ __forceinline__ int select16f(int x){
  int P = 0x40800000;
#pragma unroll
  for (int b = 22; b >= 0; --b){
    int cand = P | (1 << b);
    unsigned long long m = __ballot(x < cand);
    if ((int)__popcll(m) < 16) P = cand;
  }
  return P;
}

// Rare-path exact 16-NN (full 2048 rescan, register-light). Fires ~1e-4 now.
__device__ __forceinline__ int knn_fallback(const float4* lp, float nqx,
                                            float nqy, float nqz, int lane){
  unsigned used = 0u;
  int keep = KINF;
#pragma unroll 1
  for (int rr = 0; rr < KNN_K; rr++){
    int best = KINF;
#pragma unroll 1
    for (int j = 0; j < 32; j++){
      int c = j*64 + lane;
      float4 P = lp[c];
      float s = fmaf(P.x, nqx, fmaf(P.y, nqy, fmaf(P.z, nqz, P.w)));
      int pv = (__float_as_int(s) & 0xFFFFF800) | c;
      pv = ((used >> j) & 1u) ? KINF : pv;
      best = min(best, pv);
    }
    int gm = best;
#pragma unroll
    for (int off2 = 1; off2 < 64; off2 <<= 1)
      gm = min(gm, __shfl_xor(gm, off2, 64));
    if (lane == rr) keep = gm;
    int gc = gm & 0x7FF;
    if ((gc & 63) == lane) used |= (1u << (gc >> 6));
  }
  return keep;
}

// ---------------------------------------------------------------------------
// Kernel 0: weights -> fp16 MFMA-fragment-order tiles + cpos4 (unchanged)
// ---------------------------------------------------------------------------
__global__ void wtrans_kernel(const float* W0, const float* W1, const float* W2,
                              const float* W3, const float* Wf, const float* Wd,
                              const int* indices, const float* cpos,
                              half_t* wt, float4* cpos4){
  int idx = blockIdx.x * 256 + threadIdx.x;
  if (idx >= 110592) return;
  if (idx >= WSZ){
    int i = idx - WSZ;
    const float* cp = cpos + (size_t)indices[0] * N_C * 3;
    float x = cp[i*3 + 0], y = cp[i*3 + 1], z = cp[i*3 + 2];
    cpos4[i] = make_float4(x, y, z, fmaf(x, x, fmaf(y, y, fmaf(z, z, 4.0f))));
    return;
  }
  int base, nt, mode;            // mode: 0 plain(src), 1 W0, 2 W2, 3 Wd
  const float* src = W1;
  if (idx < 16384){ base = 0; nt = 8; mode = 1; }
  else if (idx < 32768){ base = 16384; nt = 8; mode = 0; src = W1; }
  else if (idx < 65536){ base = 32768; nt = 8; mode = 2; }
  else if (idx < 81920){ base = 65536; nt = 8; mode = 0; src = W3; }
  else if (idx < 98304){ base = 81920; nt = 8; mode = 0; src = Wf; }
  else { base = 98304; nt = 4; mode = 3; }
  int i = idx - base;
  int tile = i >> 9, e = i & 511;
  int lane = e >> 3, j = e & 7;
  int k0idx = tile / nt, tcol = tile - k0idx*nt;
  int n = tcol*16 + (lane & 15);
  int k = k0idx*32 + ((lane >> 4) << 3) + j;
  float val;
  if (mode == 0)      val = src[k*128 + n];
  else if (mode == 1) val = (k < 127) ? W0[k*128 + n] : 0.f;
  else if (mode == 2) val = (k == 127) ? 0.f
                           : ((k < 127) ? W2[k*128 + n] : W2[(k-1)*128 + n]);
  else                val = (k < 155) ? Wd[k*64 + n] : 0.f;
  wt[idx] = (half_t)val;
}

// ---------------------------------------------------------------------------
// Kernel 0.5: per-cell candidate lists. R23: window widened 7->9 cells/axis
// (lo = clamp(ci-4, 0, 7)) so interior clearance >= 0.25 — R7's regression
// was edge-zone queries (clipped kNN ball, d16 up to ~0.25) honestly failing
// the 0.1875-clearance certificate -> mass fallback. Mean list 365, LCAP 448
// (4.8 sigma). Overflow -> cnt=0 -> fallback (exact).
// ---------------------------------------------------------------------------
__global__ __launch_bounds__(512) void grid_kernel(const float4* cpos4,
    unsigned short* list, int* cnt){
  int lane = threadIdx.x & 63, wave = threadIdx.x >> 6;
  int c = blockIdx.x * 8 + wave;
  int cx = c & 15, cy = (c >> 4) & 15, cz = c >> 8;
  int lox = min(max(cx - 4, 0), 7);
  int loy = min(max(cy - 4, 0), 7);
  int loz = min(max(cz - 4, 0), 7);
  unsigned short* L = list + (size_t)c * LCAP;
  int n = 0;
#pragma unroll 1
  for (int b = 0; b < 32; b++){
    int i = b * 64 + lane;
    float4 P = cpos4[i];
    int ix = min((int)(P.x * 16.0f), 15);
    int iy = min((int)(P.y * 16.0f), 15);
    int iz = min((int)(P.z * 16.0f), 15);
    bool in = ((unsigned)(ix - lox) < 9u) && ((unsigned)(iy - loy) < 9u) &&
              ((unsigned)(iz - loz) < 9u);
    unsigned long long m = __ballot(in);
    if (m){
      int mb = __builtin_amdgcn_mbcnt_hi((unsigned)(m >> 32),
               __builtin_amdgcn_mbcnt_lo((unsigned)m, 0));
      if (in && (n + mb) < LCAP) L[n + mb] = (unsigned short)i;
      n += (int)__popcll(m);
    }
  }
  if (lane == 0) cnt[c] = (n <= LCAP) ? n : 0;
}

// ---------------------------------------------------------------------------
// Kernel 1: exact 16-NN + activation staging. Candidates from the 9-cell
// window list (~365 avg, 7 slots/lane). Certificate: d16^2 (+0.001 packing
// slop) <= squared clearance to interior window faces (>= 0.0625).
// ---------------------------------------------------------------------------
__global__ __launch_bounds__(512, 6) void knn_kernel(const int* indices,
    const float* qpts, const float4* cpos4, const unsigned short* list,
    const int* cnt, const float* codes, const float* xyzdir,
    half_t* Ain, half_t* Din){
  __shared__ float4 lp[N_C];        // 32 KB
  __shared__ int    sl[8*SLCAP];    // 4 KB
  int tid = threadIdx.x;
  int lane = tid & 63, wave = tid >> 6;
  const float* cc = codes + (size_t)indices[0] * N_C * CDIM;

  for (int c = tid; c < N_C; c += 512) lp[c] = cpos4[c];
  __syncthreads();

  int q = blockIdx.x * 8 + wave;
  float qx = qpts[q*3 + 0];
  float qy = qpts[q*3 + 1];
  float qz = qpts[q*3 + 2];
  float nqx = -2.0f*qx, nqy = -2.0f*qy, nqz = -2.0f*qz;

  int cx = min((int)(qx * 16.0f), 15);
  int cy = min((int)(qy * 16.0f), 15);
  int cz = min((int)(qz * 16.0f), 15);
  int cell = cx | (cy << 4) | (cz << 8);
  int lox = min(max(cx - 4, 0), 7);
  int loy = min(max(cy - 4, 0), 7);
  int loz = min(max(cz - 4, 0), 7);
  int nl = cnt[cell];
  const unsigned short* L = list + (size_t)cell * LCAP;

  int p[NSLOT];
  int lanemin = KINF;
#pragma unroll
  for (int it = 0; it < NSLOT; it++){
    int j = it*64 + lane;
    int idx = L[j] & 2047;            // mask stale pad -> safe LDS read
    float4 P = lp[idx];
    float s = fmaf(P.x, nqx, fmaf(P.y, nqy, fmaf(P.z, nqz, P.w)));  // > 0
    int pv = (__float_as_int(s) & 0xFFFFF800) | idx;
    pv = (j < nl) ? pv : KINF;
    asm("" : "+v"(pv));
    p[it] = pv;
    lanemin = min(lanemin, pv);
  }

  // tau = exact 16th smallest lane-min -> >= 16 candidates <= tau.
  int tau = select16f(lanemin);

  int* slw = &sl[wave * SLCAP];
  int n = 0;
#pragma unroll
  for (int it = 0; it < NSLOT; it++){
    bool c = (p[it] <= tau);
    unsigned long long m = __ballot(c);
    if (m){
      if (n <= 64){
        if (c){
          int mb = __builtin_amdgcn_mbcnt_hi((unsigned)(m >> 32),
                   __builtin_amdgcn_mbcnt_lo((unsigned)m, 0));
          slw[n + mb] = p[it];
        }
      }
      n += (int)__popcll(m);
    }
  }
  __builtin_amdgcn_wave_barrier();

  int keep = KINF;
  bool need_fb = true;
  if (n >= KNN_K && n <= 64){
    int x = (lane < n) ? slw[lane] : KINF;
    int P2 = select16f(x);            // exact 16th smallest candidate
    unsigned long long wmask = __ballot(x <= P2);
    int pos = __builtin_amdgcn_mbcnt_hi((unsigned)(wmask >> 32),
              __builtin_amdgcn_mbcnt_lo((unsigned)wmask, 0));
    if (x <= P2) slw[pos] = x;        // exactly 16 winners -> slots 0..15
    __builtin_amdgcn_wave_barrier();
    keep = (lane < KNN_K) ? slw[lane] : KINF;

    // Exactness certificate: d16^2 (upper bound) vs interior clearance^2.
    float d2u = __int_as_float(P2 & 0xFFFFF800) - 4.0f + 0.001f;
    float lofx = lox * 0.0625f, lofy = loy * 0.0625f, lofz = loz * 0.0625f;
    float cl = 1e9f;
    if (lox > 0) cl = fminf(cl, qx - lofx);
    if (lox < 7) cl = fminf(cl, lofx + 0.5625f - qx);
    if (loy > 0) cl = fminf(cl, qy - lofy);
    if (loy < 7) cl = fminf(cl, lofy + 0.5625f - qy);
    if (loz > 0) cl = fminf(cl, qz - lofz);
    if (loz < 7) cl = fminf(cl, lofz + 0.5625f - qz);
    need_fb = !(d2u <= cl * cl);
  }
  if (need_fb) keep = knn_fallback(lp, nqx, nqy, nqz, lane);

  int ci = keep & 0x7FF;
  float4 P = lp[ci];
  float dx = qx - P.x, dy = qy - P.y, dz = qz - P.z;
  float d2 = fmaf(dz, dz, fmaf(dy, dy, dx*dx));
  float w = 1.0f / (d2 + 1e-16f);
  float wm = (lane < KNN_K) ? w : 0.0f;
  wm += dppxf(wm, 1);
  wm += dppxf(wm, 2);
  wm += __shfl_xor(wm, 4, 64);
  wm += dppxf(wm, 8);
  float wn = w / wm;

  float acc = 0.f;
#pragma unroll
  for (int i = 0; i < KNN_K; i++){
    int   cb = __shfl(ci, i, 64);
    float wb = __shfl(wn, i, 64);
    acc = fmaf(wb, cc[cb*CDIM + lane], acc);
  }
  size_t arow = (size_t)q * ASTRIDE;
  Ain[arow + lane] = (half_t)acc;

  float xv = (lane < 63) ? xyzdir[(size_t)q*90 + lane] : 0.f;
  Ain[arow + 64 + lane] = (half_t)xv;
  if (lane < 8) Ain[arow + 128 + lane] = (half_t)0.f;
  if (lane < 40){
    float dv = (lane < 27) ? xyzdir[(size_t)q*90 + 63 + lane] : 0.f;
    Din[(size_t)q*DSTRIDE + lane] = (half_t)dv;
  }
}

// ---------------------------------------------------------------------------
// Kernel 2: fused MFMA MLP, 64 queries/block — R2 known-good version, frozen.
// ---------------------------------------------------------------------------
template<int NCH, int NT>
__device__ inline void mfma_pl(const half_t* act, int astride, int rowbase,
                               const half_t* wlayer, int nt, int ktbase,
                               int tcolbase, v4f acc[2][NT], int lane){
  v8h breg[NCH*NT];
#pragma unroll
  for (int c = 0; c < NCH; c++){
#pragma unroll
    for (int t = 0; t < NT; t++){
      const half_t* bp = wlayer +
          ((size_t)(((ktbase + c)*nt + tcolbase + t) << 9) + (lane << 3));
      breg[c*NT + t] = *(const v8h*)bp;
    }
  }
  int m = lane & 15, quad = lane >> 4;
#pragma unroll
  for (int c = 0; c < NCH; c++){
    v8h a0 = *(const v8h*)&act[(rowbase + m)*astride + c*32 + quad*8];
    v8h a1 = *(const v8h*)&act[(rowbase + 16 + m)*astride + c*32 + quad*8];
#pragma unroll
    for (int t = 0; t < NT; t++){
      acc[0][t] = __builtin_amdgcn_mfma_f32_16x16x32_f16(a0, breg[c*NT + t], acc[0][t], 0, 0, 0);
      acc[1][t] = __builtin_amdgcn_mfma_f32_16x16x32_f16(a1, breg[c*NT + t], acc[1][t], 0, 0, 0);
    }
  }
}

template<int NT>
__device__ inline void epilogue64(v4f acc[2][NT], half_t* outb, int rowbase,
                                  int colbase, const float* bias, bool relu,
                                  int lane){
  int n = lane & 15, quad = lane >> 4;
#pragma unroll
  for (int t = 0; t < NT; t++){
    int col = colbase + t*16 + n;
    float bv = bias[col];
#pragma unroll
    for (int g = 0; g < 2; g++){
#pragma unroll
      for (int r = 0; r < 4; r++){
        float v = acc[g][t][r] + bv;
        if (relu) v = fmaxf(v, 0.f);
        outb[(rowbase + g*16 + quad*4 + r)*ASTRIDE + col] = (half_t)v;
      }
    }
  }
}

__global__ __launch_bounds__(512, 6) void mlp_mfma(
    const half_t* Ain, const half_t* Din, const half_t* wt,
    const float* b0, const float* b1, const float* b2, const float* b3,
    const float* bfb, const float* bdb,
    const float* Wsb, const float* bsb, const float* Wrb, const float* brb,
    float* out){
  __shared__ __align__(16) half_t Abuf[64*ASTRIDE];
  __shared__ __align__(16) half_t Pbuf[64*ASTRIDE];
  __shared__ __align__(16) half_t Qbuf[64*ASTRIDE];

  int tid = threadIdx.x, lane = tid & 63, wave = tid >> 6;
  int qbase = blockIdx.x * 64;

  for (int i = tid; i < 64*17; i += 512){
    int r = i / 17, c8 = i - r*17;
    *(uint4*)&Abuf[r*ASTRIDE + (c8 << 3)] =
        *(const uint4*)&Ain[(size_t)(qbase + r)*ASTRIDE + (c8 << 3)];
  }
  __syncthreads();

  int rowbase  = (wave >> 2) * 32;
  int colq     = wave & 3;
  int colbase  = colq * 32;
  int tcolbase = colq * 2;
  v4f acc[2][2];
  v4f accd[2][1];

  const half_t* wt0 = wt;
  const half_t* wt1 = wt + 16384;
  const half_t* wt2 = wt + 32768;
  const half_t* wt3 = wt + 65536;
  const half_t* wtf = wt + 81920;
  const half_t* wtd = wt + 98304;

#define ZACC22() { for (int g_ = 0; g_ < 2; g_++) for (int t_ = 0; t_ < 2; t_++) \
                   for (int e_ = 0; e_ < 4; e_++) acc[g_][t_][e_] = 0.f; }

  // L0: A @ W0 -> P (relu)
  ZACC22();
  mfma_pl<4,2>(Abuf, ASTRIDE, rowbase, wt0, 8, 0, tcolbase, acc, lane);
  epilogue64<2>(acc, Pbuf, rowbase, colbase, b0, true, lane);
  __syncthreads();

  // L1: P @ W1 -> Q (relu)
  ZACC22();
  mfma_pl<4,2>(Pbuf, ASTRIDE, rowbase, wt1, 8, 0, tcolbase, acc, lane);
  epilogue64<2>(acc, Qbuf, rowbase, colbase, b1, true, lane);
  __syncthreads();

  // L2: [input_xyz | h1] @ W2 -> P (relu)   (K = 256)
  ZACC22();
  mfma_pl<4,2>(Abuf, ASTRIDE, rowbase, wt2, 8, 0, tcolbase, acc, lane);
  mfma_pl<4,2>(Qbuf, ASTRIDE, rowbase, wt2, 8, 4, tcolbase, acc, lane);
  epilogue64<2>(acc, Pbuf, rowbase, colbase, b2, true, lane);
  __syncthreads();

  // L3: P @ W3 -> A (h3, kept for sigma; input_xyz dead)
  ZACC22();
  mfma_pl<4,2>(Pbuf, ASTRIDE, rowbase, wt3, 8, 0, tcolbase, acc, lane);
  epilogue64<2>(acc, Abuf, rowbase, colbase, b3, true, lane);
  __syncthreads();

  // Wf: A(h3) @ Wf -> P (no relu)
  ZACC22();
  mfma_pl<4,2>(Abuf, ASTRIDE, rowbase, wtf, 8, 0, tcolbase, acc, lane);
  epilogue64<2>(acc, Pbuf, rowbase, colbase, bfb, false, lane);
  __syncthreads();

  // Wd: [P(final) | Din(dir, straight from global/L2)] @ Wd -> Q[:,0:64]
#pragma unroll
  for (int g_ = 0; g_ < 2; g_++)
#pragma unroll
    for (int e_ = 0; e_ < 4; e_++) accd[g_][0][e_] = 0.f;
  mfma_pl<4,1>(Pbuf, ASTRIDE, rowbase, wtd, 4, 0, colq, accd, lane);
  mfma_pl<1,1>(Din + (size_t)qbase*DSTRIDE, DSTRIDE, rowbase, wtd, 4, 4, colq,
               accd, lane);
  epilogue64<1>(accd, Qbuf, rowbase, colq * 16, bdb, true, lane);
  __syncthreads();

  // Tail: sigma = h3(Abuf).Ws + bs ; rgb = d(Qbuf).Wr + br  (8 thr/query)
  {
    int q = tid >> 3, part = tid & 7;
    float s = 0.f;
#pragma unroll
    for (int k = 0; k < 16; k++){
      int kk = part*16 + k;
      s = fmaf((float)Abuf[q*ASTRIDE + kk], Wsb[kk], s);
    }
    s += __shfl_xor(s, 1, 64); s += __shfl_xor(s, 2, 64); s += __shfl_xor(s, 4, 64);

    float r3[3];
#pragma unroll
    for (int c2 = 0; c2 < 3; c2++){
      float rv = 0.f;
#pragma unroll
      for (int k = 0; k < 8; k++){
        int kk = part*8 + k;
        rv = fmaf((float)Qbuf[q*ASTRIDE + kk], Wrb[kk*3 + c2], rv);
      }
      rv += __shfl_xor(rv, 1, 64); rv += __shfl_xor(rv, 2, 64); rv += __shfl_xor(rv, 4, 64);
      r3[c2] = rv;
    }
    if (part == 0){
      size_t ob = ((size_t)(qbase + q)) * 4;
      out[ob + 0] = r3[0] + brb[0];
      out[ob + 1] = r3[1] + brb[1];
      out[ob + 2] = r3[2] + brb[2];
      out[ob + 3] = s + bsb[0];
    }
  }
}

// ---------------------------------------------------------------------------
extern "C" void kernel_launch(void* const* d_in, const int* in_sizes, int n_in,
                              void* d_out, int out_size, void* d_ws, size_t ws_size,
                              hipStream_t stream){
  (void)in_sizes; (void)n_in; (void)out_size; (void)ws_size;

  const int*   indices = (const int*)d_in[0];
  const float* qpts    = (const float*)d_in[1];
  const float* xyzdir  = (const float*)d_in[2];
  const float* cpos    = (const float*)d_in[3];
  const float* codes   = (const float*)d_in[4];
  const float* W0 = (const float*)d_in[5];
  const float* b0 = (const float*)d_in[6];
  const float* W1 = (const float*)d_in[7];
  const float* b1 = (const float*)d_in[8];
  const float* W2 = (const float*)d_in[9];
  const float* b2 = (const float*)d_in[10];
  const float* W3 = (const float*)d_in[11];
  const float* b3 = (const float*)d_in[12];
  const float* Wf = (const float*)d_in[13];
  const float* bf = (const float*)d_in[14];
  const float* Wd = (const float*)d_in[15];
  const float* bd = (const float*)d_in[16];
  const float* Ws = (const float*)d_in[17];
  const float* bs = (const float*)d_in[18];
  const float* Wr = (const float*)d_in[19];
  const float* br = (const float*)d_in[20];

  // ws layout (16-B aligned): Ain | Din | wt | cpos4 | list | cnt
  half_t* Ain            = (half_t*)d_ws;                          // 17,825,792
  half_t* Din            = (half_t*)((char*)d_ws + 17825792);      //  5,242,880
  half_t* wt             = (half_t*)((char*)d_ws + 23068672);      //    217,088
  float4* cpos4          = (float4*)((char*)d_ws + 23285760);      //     32,768
  unsigned short* list   = (unsigned short*)((char*)d_ws + 23318528); // 3,670,016
  int* cnt               = (int*)((char*)d_ws + 26988544);         //     16,384

  wtrans_kernel<<<(110592 + 255)/256, 256, 0, stream>>>(W0, W1, W2, W3, Wf, Wd,
                                                        indices, cpos, wt, cpos4);
  grid_kernel<<<GCELLS/8, 512, 0, stream>>>(cpos4, list, cnt);
  knn_kernel<<<N_Q/8, 512, 0, stream>>>(indices, qpts, cpos4, list, cnt,
                                        codes, xyzdir, Ain, Din);
  mlp_mfma<<<N_Q/64, 512, 0, stream>>>(Ain, Din, wt,
                                       b0, b1, b2, b3, bf, bd, Ws, bs, Wr, br,
                                       (float*)d_out);
}

// Round 9
// 208.912 us; speedup vs baseline: 3.3826x; 3.3826x over previous
//
#include <hip/hip_runtime.h>

#define N_Q   65536
#define N_C   2048
#define KNN_K 16
#define CDIM  64
#define SLCAP 128
#define KINF  0x7FFFFFFF
#define WSZ   108544  // halves per weight image

#define GN     16     // grid cells per axis
#define GCELLS 4096
#define LCAP   448    // per-cell candidate-list capacity (u16), 7 slots/lane
#define NSLOT  7

typedef _Float16 half_t;
typedef float v4f __attribute__((ext_vector_type(4)));
typedef half_t v8h __attribute__((ext_vector_type(8)));

#define ASTRIDE 136   // 128 + 8 pad (halves); row = 272 B = 17*16 B
#define DSTRIDE 40    // 32 + 8 pad

// ---------------------------------------------------------------------------
// DPP lane-xor (wm tree reduction).
// ---------------------------------------------------------------------------
__device__ __forceinline__ int dppx(int v, int j){
  if (j == 1) return __builtin_amdgcn_mov_dpp(v, 0xB1,  0xF, 0xF, true);
  if (j == 2) return __builtin_amdgcn_mov_dpp(v, 0x4E,  0xF, 0xF, true);
  if (j == 8) return __builtin_amdgcn_mov_dpp(v, 0x128, 0xF, 0xF, true);
  return __shfl_xor(v, j, 64);
}
__device__ __forceinline__ float dppxf(float v, int j){
  return __int_as_float(dppx(__float_as_int(v), j));
}

// Exact 16th-smallest of 64 per-lane positive ints, FULL-RANGE bitwise
// binary search (31 rounds). R9 FIX: the R6 "optimized" fixed-prefix
// variant assumed packed s in [4,8), but s = d^2 + 4 - |q|^2 can drop to
// ~1 -> tau degenerated to the prefix -> n > 64 -> 100% fallback (the
// entire R7/R8 regression). Full-range search (proven in R5) has no
// range assumption; costs only ~16 extra VALU per call.
__device__ __forceinline__ int select16th(int x){
  int P = 0;
#pragma unroll
  for (int b = 30; b >= 0; --b){
    int cand = P | (1 << b);
    unsigned long long m = __ballot(x < cand);
    if ((int)__popcll(m) < 16) P = cand;
  }
  return P;
}

// Rare-path exact 16-NN (full 2048 rescan, register-light).
__device__ __forceinline__ int knn_fallback(const float4* lp, float nqx,
                                            float nqy, float nqz, int lane){
  unsigned used = 0u;
  int keep = KINF;
#pragma unroll 1
  for (int rr = 0; rr < KNN_K; rr++){
    int best = KINF;
#pragma unroll 1
    for (int j = 0; j < 32; j++){
      int c = j*64 + lane;
      float4 P = lp[c];
      float s = fmaf(P.x, nqx, fmaf(P.y, nqy, fmaf(P.z, nqz, P.w)));
      int pv = (__float_as_int(s) & 0xFFFFF800) | c;
      pv = ((used >> j) & 1u) ? KINF : pv;
      best = min(best, pv);
    }
    int gm = best;
#pragma unroll
    for (int off2 = 1; off2 < 64; off2 <<= 1)
      gm = min(gm, __shfl_xor(gm, off2, 64));
    if (lane == rr) keep = gm;
    int gc = gm & 0x7FF;
    if ((gc & 63) == lane) used |= (1u << (gc >> 6));
  }
  return keep;
}

// ---------------------------------------------------------------------------
// Kernel 0: weights -> fp16 MFMA-fragment-order tiles + cpos4 (unchanged)
// ---------------------------------------------------------------------------
__global__ void wtrans_kernel(const float* W0, const float* W1, const float* W2,
                              const float* W3, const float* Wf, const float* Wd,
                              const int* indices, const float* cpos,
                              half_t* wt, float4* cpos4){
  int idx = blockIdx.x * 256 + threadIdx.x;
  if (idx >= 110592) return;
  if (idx >= WSZ){
    int i = idx - WSZ;
    const float* cp = cpos + (size_t)indices[0] * N_C * 3;
    float x = cp[i*3 + 0], y = cp[i*3 + 1], z = cp[i*3 + 2];
    cpos4[i] = make_float4(x, y, z, fmaf(x, x, fmaf(y, y, fmaf(z, z, 4.0f))));
    return;
  }
  int base, nt, mode;            // mode: 0 plain(src), 1 W0, 2 W2, 3 Wd
  const float* src = W1;
  if (idx < 16384){ base = 0; nt = 8; mode = 1; }
  else if (idx < 32768){ base = 16384; nt = 8; mode = 0; src = W1; }
  else if (idx < 65536){ base = 32768; nt = 8; mode = 2; }
  else if (idx < 81920){ base = 65536; nt = 8; mode = 0; src = W3; }
  else if (idx < 98304){ base = 81920; nt = 8; mode = 0; src = Wf; }
  else { base = 98304; nt = 4; mode = 3; }
  int i = idx - base;
  int tile = i >> 9, e = i & 511;
  int lane = e >> 3, j = e & 7;
  int k0idx = tile / nt, tcol = tile - k0idx*nt;
  int n = tcol*16 + (lane & 15);
  int k = k0idx*32 + ((lane >> 4) << 3) + j;
  float val;
  if (mode == 0)      val = src[k*128 + n];
  else if (mode == 1) val = (k < 127) ? W0[k*128 + n] : 0.f;
  else if (mode == 2) val = (k == 127) ? 0.f
                           : ((k < 127) ? W2[k*128 + n] : W2[(k-1)*128 + n]);
  else                val = (k < 155) ? Wd[k*64 + n] : 0.f;
  wt[idx] = (half_t)val;
}

// ---------------------------------------------------------------------------
// Kernel 0.5: per-cell candidate lists, 9-cell window (unchanged from R8).
// ---------------------------------------------------------------------------
__global__ __launch_bounds__(512) void grid_kernel(const float4* cpos4,
    unsigned short* list, int* cnt){
  int lane = threadIdx.x & 63, wave = threadIdx.x >> 6;
  int c = blockIdx.x * 8 + wave;
  int cx = c & 15, cy = (c >> 4) & 15, cz = c >> 8;
  int lox = min(max(cx - 4, 0), 7);
  int loy = min(max(cy - 4, 0), 7);
  int loz = min(max(cz - 4, 0), 7);
  unsigned short* L = list + (size_t)c * LCAP;
  int n = 0;
#pragma unroll 1
  for (int b = 0; b < 32; b++){
    int i = b * 64 + lane;
    float4 P = cpos4[i];
    int ix = min((int)(P.x * 16.0f), 15);
    int iy = min((int)(P.y * 16.0f), 15);
    int iz = min((int)(P.z * 16.0f), 15);
    bool in = ((unsigned)(ix - lox) < 9u) && ((unsigned)(iy - loy) < 9u) &&
              ((unsigned)(iz - loz) < 9u);
    unsigned long long m = __ballot(in);
    if (m){
      int mb = __builtin_amdgcn_mbcnt_hi((unsigned)(m >> 32),
               __builtin_amdgcn_mbcnt_lo((unsigned)m, 0));
      if (in && (n + mb) < LCAP) L[n + mb] = (unsigned short)i;
      n += (int)__popcll(m);
    }
  }
  if (lane == 0) cnt[c] = (n <= LCAP) ? n : 0;
}

// ---------------------------------------------------------------------------
// Kernel 1: exact 16-NN + activation staging. R9: full-range select16th
// (fixes the degenerate-tau bug) + certificate decode adds |q|^2 back
// (s = d^2 + 4 - |q|^2, so d^2 = s - 4 + |q|^2).
// ---------------------------------------------------------------------------
__global__ __launch_bounds__(512, 6) void knn_kernel(const int* indices,
    const float* qpts, const float4* cpos4, const unsigned short* list,
    const int* cnt, const float* codes, const float* xyzdir,
    half_t* Ain, half_t* Din){
  __shared__ float4 lp[N_C];        // 32 KB
  __shared__ int    sl[8*SLCAP];    // 4 KB
  int tid = threadIdx.x;
  int lane = tid & 63, wave = tid >> 6;
  const float* cc = codes + (size_t)indices[0] * N_C * CDIM;

  for (int c = tid; c < N_C; c += 512) lp[c] = cpos4[c];
  __syncthreads();

  int q = blockIdx.x * 8 + wave;
  float qx = qpts[q*3 + 0];
  float qy = qpts[q*3 + 1];
  float qz = qpts[q*3 + 2];
  float nqx = -2.0f*qx, nqy = -2.0f*qy, nqz = -2.0f*qz;
  float qq = fmaf(qx, qx, fmaf(qy, qy, qz*qz));   // |q|^2

  int cx = min((int)(qx * 16.0f), 15);
  int cy = min((int)(qy * 16.0f), 15);
  int cz = min((int)(qz * 16.0f), 15);
  int cell = cx | (cy << 4) | (cz << 8);
  int lox = min(max(cx - 4, 0), 7);
  int loy = min(max(cy - 4, 0), 7);
  int loz = min(max(cz - 4, 0), 7);
  int nl = cnt[cell];
  const unsigned short* L = list + (size_t)cell * LCAP;

  int p[NSLOT];
  int lanemin = KINF;
#pragma unroll
  for (int it = 0; it < NSLOT; it++){
    int j = it*64 + lane;
    int idx = L[j] & 2047;            // mask stale pad -> safe LDS read
    float4 P = lp[idx];
    float s = fmaf(P.x, nqx, fmaf(P.y, nqy, fmaf(P.z, nqz, P.w)));  // > 0
    int pv = (__float_as_int(s) & 0xFFFFF800) | idx;
    pv = (j < nl) ? pv : KINF;
    asm("" : "+v"(pv));
    p[it] = pv;
    lanemin = min(lanemin, pv);
  }

  // tau = exact 16th smallest lane-min -> >= 16 candidates <= tau.
  int tau = select16th(lanemin);

  int* slw = &sl[wave * SLCAP];
  int n = 0;
#pragma unroll
  for (int it = 0; it < NSLOT; it++){
    bool c = (p[it] <= tau);
    unsigned long long m = __ballot(c);
    if (m){
      if (n <= 64){
        if (c){
          int mb = __builtin_amdgcn_mbcnt_hi((unsigned)(m >> 32),
                   __builtin_amdgcn_mbcnt_lo((unsigned)m, 0));
          slw[n + mb] = p[it];
        }
      }
      n += (int)__popcll(m);
    }
  }
  __builtin_amdgcn_wave_barrier();

  int keep = KINF;
  bool need_fb = true;
  if (n >= KNN_K && n <= 64){
    int x = (lane < n) ? slw[lane] : KINF;
    int P2 = select16th(x);           // exact 16th smallest candidate
    unsigned long long wmask = __ballot(x <= P2);
    int pos = __builtin_amdgcn_mbcnt_hi((unsigned)(wmask >> 32),
              __builtin_amdgcn_mbcnt_lo((unsigned)wmask, 0));
    if (x <= P2) slw[pos] = x;        // exactly 16 winners -> slots 0..15
    __builtin_amdgcn_wave_barrier();
    keep = (lane < KNN_K) ? slw[lane] : KINF;

    // Certificate: true d16^2 upper bound vs interior clearance^2.
    // s = d^2 + 4 - |q|^2  =>  d^2 = s - 4 + |q|^2; truncation < 2^-10.
    float d2u = __int_as_float(P2 & 0xFFFFF800) - 4.0f + qq + 0.002f;
    float lofx = lox * 0.0625f, lofy = loy * 0.0625f, lofz = loz * 0.0625f;
    float cl = 1e9f;
    if (lox > 0) cl = fminf(cl, qx - lofx);
    if (lox < 7) cl = fminf(cl, lofx + 0.5625f - qx);
    if (loy > 0) cl = fminf(cl, qy - lofy);
    if (loy < 7) cl = fminf(cl, lofy + 0.5625f - qy);
    if (loz > 0) cl = fminf(cl, qz - lofz);
    if (loz < 7) cl = fminf(cl, lofz + 0.5625f - qz);
    need_fb = !(d2u <= cl * cl);
  }
  if (need_fb) keep = knn_fallback(lp, nqx, nqy, nqz, lane);

  int ci = keep & 0x7FF;
  float4 P = lp[ci];
  float dx = qx - P.x, dy = qy - P.y, dz = qz - P.z;
  float d2 = fmaf(dz, dz, fmaf(dy, dy, dx*dx));
  float w = 1.0f / (d2 + 1e-16f);
  float wm = (lane < KNN_K) ? w : 0.0f;
  wm += dppxf(wm, 1);
  wm += dppxf(wm, 2);
  wm += __shfl_xor(wm, 4, 64);
  wm += dppxf(wm, 8);
  float wn = w / wm;

  float acc = 0.f;
#pragma unroll
  for (int i = 0; i < KNN_K; i++){
    int   cb = __shfl(ci, i, 64);
    float wb = __shfl(wn, i, 64);
    acc = fmaf(wb, cc[cb*CDIM + lane], acc);
  }
  size_t arow = (size_t)q * ASTRIDE;
  Ain[arow + lane] = (half_t)acc;

  float xv = (lane < 63) ? xyzdir[(size_t)q*90 + lane] : 0.f;
  Ain[arow + 64 + lane] = (half_t)xv;
  if (lane < 8) Ain[arow + 128 + lane] = (half_t)0.f;
  if (lane < 40){
    float dv = (lane < 27) ? xyzdir[(size_t)q*90 + 63 + lane] : 0.f;
    Din[(size_t)q*DSTRIDE + lane] = (half_t)dv;
  }
}

// ---------------------------------------------------------------------------
// Kernel 2: fused MFMA MLP, 64 queries/block — R2 known-good version, frozen.
// ---------------------------------------------------------------------------
template<int NCH, int NT>
__device__ inline void mfma_pl(const half_t* act, int astride, int rowbase,
                               const half_t* wlayer, int nt, int ktbase,
                               int tcolbase, v4f acc[2][NT], int lane){
  v8h breg[NCH*NT];
#pragma unroll
  for (int c = 0; c < NCH; c++){
#pragma unroll
    for (int t = 0; t < NT; t++){
      const half_t* bp = wlayer +
          ((size_t)(((ktbase + c)*nt + tcolbase + t) << 9) + (lane << 3));
      breg[c*NT + t] = *(const v8h*)bp;
    }
  }
  int m = lane & 15, quad = lane >> 4;
#pragma unroll
  for (int c = 0; c < NCH; c++){
    v8h a0 = *(const v8h*)&act[(rowbase + m)*astride + c*32 + quad*8];
    v8h a1 = *(const v8h*)&act[(rowbase + 16 + m)*astride + c*32 + quad*8];
#pragma unroll
    for (int t = 0; t < NT; t++){
      acc[0][t] = __builtin_amdgcn_mfma_f32_16x16x32_f16(a0, breg[c*NT + t], acc[0][t], 0, 0, 0);
      acc[1][t] = __builtin_amdgcn_mfma_f32_16x16x32_f16(a1, breg[c*NT + t], acc[1][t], 0, 0, 0);
    }
  }
}

template<int NT>
__device__ inline void epilogue64(v4f acc[2][NT], half_t* outb, int rowbase,
                                  int colbase, const float* bias, bool relu,
                                  int lane){
  int n = lane & 15, quad = lane >> 4;
#pragma unroll
  for (int t = 0; t < NT; t++){
    int col = colbase + t*16 + n;
    float bv = bias[col];
#pragma unroll
    for (int g = 0; g < 2; g++){
#pragma unroll
      for (int r = 0; r < 4; r++){
        float v = acc[g][t][r] + bv;
        if (relu) v = fmaxf(v, 0.f);
        outb[(rowbase + g*16 + quad*4 + r)*ASTRIDE + col] = (half_t)v;
      }
    }
  }
}

__global__ __launch_bounds__(512, 6) void mlp_mfma(
    const half_t* Ain, const half_t* Din, const half_t* wt,
    const float* b0, const float* b1, const float* b2, const float* b3,
    const float* bfb, const float* bdb,
    const float* Wsb, const float* bsb, const float* Wrb, const float* brb,
    float* out){
  __shared__ __align__(16) half_t Abuf[64*ASTRIDE];
  __shared__ __align__(16) half_t Pbuf[64*ASTRIDE];
  __shared__ __align__(16) half_t Qbuf[64*ASTRIDE];

  int tid = threadIdx.x, lane = tid & 63, wave = tid >> 6;
  int qbase = blockIdx.x * 64;

  for (int i = tid; i < 64*17; i += 512){
    int r = i / 17, c8 = i - r*17;
    *(uint4*)&Abuf[r*ASTRIDE + (c8 << 3)] =
        *(const uint4*)&Ain[(size_t)(qbase + r)*ASTRIDE + (c8 << 3)];
  }
  __syncthreads();

  int rowbase  = (wave >> 2) * 32;
  int colq     = wave & 3;
  int colbase  = colq * 32;
  int tcolbase = colq * 2;
  v4f acc[2][2];
  v4f accd[2][1];

  const half_t* wt0 = wt;
  const half_t* wt1 = wt + 16384;
  const half_t* wt2 = wt + 32768;
  const half_t* wt3 = wt + 65536;
  const half_t* wtf = wt + 81920;
  const half_t* wtd = wt + 98304;

#define ZACC22() { for (int g_ = 0; g_ < 2; g_++) for (int t_ = 0; t_ < 2; t_++) \
                   for (int e_ = 0; e_ < 4; e_++) acc[g_][t_][e_] = 0.f; }

  // L0: A @ W0 -> P (relu)
  ZACC22();
  mfma_pl<4,2>(Abuf, ASTRIDE, rowbase, wt0, 8, 0, tcolbase, acc, lane);
  epilogue64<2>(acc, Pbuf, rowbase, colbase, b0, true, lane);
  __syncthreads();

  // L1: P @ W1 -> Q (relu)
  ZACC22();
  mfma_pl<4,2>(Pbuf, ASTRIDE, rowbase, wt1, 8, 0, tcolbase, acc, lane);
  epilogue64<2>(acc, Qbuf, rowbase, colbase, b1, true, lane);
  __syncthreads();

  // L2: [input_xyz | h1] @ W2 -> P (relu)   (K = 256)
  ZACC22();
  mfma_pl<4,2>(Abuf, ASTRIDE, rowbase, wt2, 8, 0, tcolbase, acc, lane);
  mfma_pl<4,2>(Qbuf, ASTRIDE, rowbase, wt2, 8, 4, tcolbase, acc, lane);
  epilogue64<2>(acc, Pbuf, rowbase, colbase, b2, true, lane);
  __syncthreads();

  // L3: P @ W3 -> A (h3, kept for sigma; input_xyz dead)
  ZACC22();
  mfma_pl<4,2>(Pbuf, ASTRIDE, rowbase, wt3, 8, 0, tcolbase, acc, lane);
  epilogue64<2>(acc, Abuf, rowbase, colbase, b3, true, lane);
  __syncthreads();

  // Wf: A(h3) @ Wf -> P (no relu)
  ZACC22();
  mfma_pl<4,2>(Abuf, ASTRIDE, rowbase, wtf, 8, 0, tcolbase, acc, lane);
  epilogue64<2>(acc, Pbuf, rowbase, colbase, bfb, false, lane);
  __syncthreads();

  // Wd: [P(final) | Din(dir, straight from global/L2)] @ Wd -> Q[:,0:64]
#pragma unroll
  for (int g_ = 0; g_ < 2; g_++)
#pragma unroll
    for (int e_ = 0; e_ < 4; e_++) accd[g_][0][e_] = 0.f;
  mfma_pl<4,1>(Pbuf, ASTRIDE, rowbase, wtd, 4, 0, colq, accd, lane);
  mfma_pl<1,1>(Din + (size_t)qbase*DSTRIDE, DSTRIDE, rowbase, wtd, 4, 4, colq,
               accd, lane);
  epilogue64<1>(accd, Qbuf, rowbase, colq * 16, bdb, true, lane);
  __syncthreads();

  // Tail: sigma = h3(Abuf).Ws + bs ; rgb = d(Qbuf).Wr + br  (8 thr/query)
  {
    int q = tid >> 3, part = tid & 7;
    float s = 0.f;
#pragma unroll
    for (int k = 0; k < 16; k++){
      int kk = part*16 + k;
      s = fmaf((float)Abuf[q*ASTRIDE + kk], Wsb[kk], s);
    }
    s += __shfl_xor(s, 1, 64); s += __shfl_xor(s, 2, 64); s += __shfl_xor(s, 4, 64);

    float r3[3];
#pragma unroll
    for (int c2 = 0; c2 < 3; c2++){
      float rv = 0.f;
#pragma unroll
      for (int k = 0; k < 8; k++){
        int kk = part*8 + k;
        rv = fmaf((float)Qbuf[q*ASTRIDE + kk], Wrb[kk*3 + c2], rv);
      }
      rv += __shfl_xor(rv, 1, 64); rv += __shfl_xor(rv, 2, 64); rv += __shfl_xor(rv, 4, 64);
      r3[c2] = rv;
    }
    if (part == 0){
      size_t ob = ((size_t)(qbase + q)) * 4;
      out[ob + 0] = r3[0] + brb[0];
      out[ob + 1] = r3[1] + brb[1];
      out[ob + 2] = r3[2] + brb[2];
      out[ob + 3] = s + bsb[0];
    }
  }
}

// ---------------------------------------------------------------------------
extern "C" void kernel_launch(void* const* d_in, const int* in_sizes, int n_in,
                              void* d_out, int out_size, void* d_ws, size_t ws_size,
                              hipStream_t stream){
  (void)in_sizes; (void)n_in; (void)out_size; (void)ws_size;

  const int*   indices = (const int*)d_in[0];
  const float* qpts    = (const float*)d_in[1];
  const float* xyzdir  = (const float*)d_in[2];
  const float* cpos    = (const float*)d_in[3];
  const float* codes   = (const float*)d_in[4];
  const float* W0 = (const float*)d_in[5];
  const float* b0 = (const float*)d_in[6];
  const float* W1 = (const float*)d_in[7];
  const float* b1 = (const float*)d_in[8];
  const float* W2 = (const float*)d_in[9];
  const float* b2 = (const float*)d_in[10];
  const float* W3 = (const float*)d_in[11];
  const float* b3 = (const float*)d_in[12];
  const float* Wf = (const float*)d_in[13];
  const float* bf = (const float*)d_in[14];
  const float* Wd = (const float*)d_in[15];
  const float* bd = (const float*)d_in[16];
  const float* Ws = (const float*)d_in[17];
  const float* bs = (const float*)d_in[18];
  const float* Wr = (const float*)d_in[19];
  const float* br = (const float*)d_in[20];

  // ws layout (16-B aligned): Ain | Din | wt | cpos4 | list | cnt
  half_t* Ain            = (half_t*)d_ws;                          // 17,825,792
  half_t* Din            = (half_t*)((char*)d_ws + 17825792);      //  5,242,880
  half_t* wt             = (half_t*)((char*)d_ws + 23068672);      //    217,088
  float4* cpos4          = (float4*)((char*)d_ws + 23285760);      //     32,768
  unsigned short* list   = (unsigned short*)((char*)d_ws + 23318528); // 3,670,016
  int* cnt               = (int*)((char*)d_ws + 26988544);         //     16,384

  wtrans_kernel<<<(110592 + 255)/256, 256, 0, stream>>>(W0, W1, W2, W3, Wf, Wd,
                                                        indices, cpos, wt, cpos4);
  grid_kernel<<<GCELLS/8, 512, 0, stream>>>(cpos4, list, cnt);
  knn_kernel<<<N_Q/8, 512, 0, stream>>>(indices, qpts, cpos4, list, cnt,
                                        codes, xyzdir, Ain, Din);
  mlp_mfma<<<N_Q/64, 512, 0, stream>>>(Ain, Din, wt,
                                       b0, b1, b2, b3, bf, bd, Ws, bs, Wr, br,
                                       (float*)d_out);
}

// Round 10
// 201.619 us; speedup vs baseline: 3.5050x; 1.0362x over previous
//
#include <hip/hip_runtime.h>

#define N_Q   65536
#define N_C   2048
#define KNN_K 16
#define CDIM  64
#define SLCAP 128
#define KINF  0x7FFFFFFF
#define WSZ   108544  // halves per weight image

#define GN     16     // grid cells per axis
#define GCELLS 4096
#define LCAP   448    // per-cell candidate capacity (u16)
#define LSTORE 512    // padded storage per cell (u16) for safe dwordx4 reads
#define NSLOT  8      // candidate slots per lane (one 16B load)

typedef _Float16 half_t;
typedef float v4f __attribute__((ext_vector_type(4)));
typedef half_t v8h __attribute__((ext_vector_type(8)));
typedef unsigned short u16x8 __attribute__((ext_vector_type(8)));

#define ASTRIDE 136   // 128 + 8 pad (halves); row = 272 B = 17*16 B
#define DSTRIDE 40    // 32 + 8 pad

// ---------------------------------------------------------------------------
// DPP lane-xor (wm tree reduction).
// ---------------------------------------------------------------------------
__device__ __forceinline__ int dppx(int v, int j){
  if (j == 1) return __builtin_amdgcn_mov_dpp(v, 0xB1,  0xF, 0xF, true);
  if (j == 2) return __builtin_amdgcn_mov_dpp(v, 0x4E,  0xF, 0xF, true);
  if (j == 8) return __builtin_amdgcn_mov_dpp(v, 0x128, 0xF, 0xF, true);
  return __shfl_xor(v, j, 64);
}
__device__ __forceinline__ float dppxf(float v, int j){
  return __int_as_float(dppx(__float_as_int(v), j));
}

// Exact 16th-smallest, full-range 31-round bitwise binary search (R9-proven).
__device__ __forceinline__ int select16th(int x){
  int P = 0;
#pragma unroll
  for (int b = 30; b >= 0; --b){
    int cand = P | (1 << b);
    unsigned long long m = __ballot(x < cand);
    if ((int)__popcll(m) < 16) P = cand;
  }
  return P;
}

// R10: truncated tau search — bits 30..11 only, then fill the 11 index bits
// with 1s. Invariant: count(x < P + 0x800) >= 16, so tau = P|0x7FF still
// admits >= 16 candidates; n <= 64 is checked downstream (fallback if not).
// Saves 11 dependent ballot rounds; winner select stays exact.
__device__ __forceinline__ int select16_tau(int x){
  int P = 0;
#pragma unroll
  for (int b = 30; b >= 11; --b){
    int cand = P | (1 << b);
    unsigned long long m = __ballot(x < cand);
    if ((int)__popcll(m) < 16) P = cand;
  }
  return P | 0x7FF;
}

// Rare-path exact 16-NN (full 2048 rescan, register-light).
__device__ __forceinline__ int knn_fallback(const float4* lp, float nqx,
                                            float nqy, float nqz, int lane){
  unsigned used = 0u;
  int keep = KINF;
#pragma unroll 1
  for (int rr = 0; rr < KNN_K; rr++){
    int best = KINF;
#pragma unroll 1
    for (int j = 0; j < 32; j++){
      int c = j*64 + lane;
      float4 P = lp[c];
      float s = fmaf(P.x, nqx, fmaf(P.y, nqy, fmaf(P.z, nqz, P.w)));
      int pv = (__float_as_int(s) & 0xFFFFF800) | c;
      pv = ((used >> j) & 1u) ? KINF : pv;
      best = min(best, pv);
    }
    int gm = best;
#pragma unroll
    for (int off2 = 1; off2 < 64; off2 <<= 1)
      gm = min(gm, __shfl_xor(gm, off2, 64));
    if (lane == rr) keep = gm;
    int gc = gm & 0x7FF;
    if ((gc & 63) == lane) used |= (1u << (gc >> 6));
  }
  return keep;
}

// ---------------------------------------------------------------------------
// Kernel 0: weights -> fp16 MFMA-fragment-order tiles + cpos4 (unchanged)
// ---------------------------------------------------------------------------
__global__ void wtrans_kernel(const float* W0, const float* W1, const float* W2,
                              const float* W3, const float* Wf, const float* Wd,
                              const int* indices, const float* cpos,
                              half_t* wt, float4* cpos4){
  int idx = blockIdx.x * 256 + threadIdx.x;
  if (idx >= 110592) return;
  if (idx >= WSZ){
    int i = idx - WSZ;
    const float* cp = cpos + (size_t)indices[0] * N_C * 3;
    float x = cp[i*3 + 0], y = cp[i*3 + 1], z = cp[i*3 + 2];
    cpos4[i] = make_float4(x, y, z, fmaf(x, x, fmaf(y, y, fmaf(z, z, 4.0f))));
    return;
  }
  int base, nt, mode;            // mode: 0 plain(src), 1 W0, 2 W2, 3 Wd
  const float* src = W1;
  if (idx < 16384){ base = 0; nt = 8; mode = 1; }
  else if (idx < 32768){ base = 16384; nt = 8; mode = 0; src = W1; }
  else if (idx < 65536){ base = 32768; nt = 8; mode = 2; }
  else if (idx < 81920){ base = 65536; nt = 8; mode = 0; src = W3; }
  else if (idx < 98304){ base = 81920; nt = 8; mode = 0; src = Wf; }
  else { base = 98304; nt = 4; mode = 3; }
  int i = idx - base;
  int tile = i >> 9, e = i & 511;
  int lane = e >> 3, j = e & 7;
  int k0idx = tile / nt, tcol = tile - k0idx*nt;
  int n = tcol*16 + (lane & 15);
  int k = k0idx*32 + ((lane >> 4) << 3) + j;
  float val;
  if (mode == 0)      val = src[k*128 + n];
  else if (mode == 1) val = (k < 127) ? W0[k*128 + n] : 0.f;
  else if (mode == 2) val = (k == 127) ? 0.f
                           : ((k < 127) ? W2[k*128 + n] : W2[(k-1)*128 + n]);
  else                val = (k < 155) ? Wd[k*64 + n] : 0.f;
  wt[idx] = (half_t)val;
}

// ---------------------------------------------------------------------------
// Kernel 0.5: per-cell candidate lists, 9-cell window (logic unchanged;
// storage stride now LSTORE=512 u16 so knn can read one dwordx4 per lane).
// ---------------------------------------------------------------------------
__global__ __launch_bounds__(512) void grid_kernel(const float4* cpos4,
    unsigned short* list, int* cnt){
  int lane = threadIdx.x & 63, wave = threadIdx.x >> 6;
  int c = blockIdx.x * 8 + wave;
  int cx = c & 15, cy = (c >> 4) & 15, cz = c >> 8;
  int lox = min(max(cx - 4, 0), 7);
  int loy = min(max(cy - 4, 0), 7);
  int loz = min(max(cz - 4, 0), 7);
  unsigned short* L = list + (size_t)c * LSTORE;
  int n = 0;
#pragma unroll 1
  for (int b = 0; b < 32; b++){
    int i = b * 64 + lane;
    float4 P = cpos4[i];
    int ix = min((int)(P.x * 16.0f), 15);
    int iy = min((int)(P.y * 16.0f), 15);
    int iz = min((int)(P.z * 16.0f), 15);
    bool in = ((unsigned)(ix - lox) < 9u) && ((unsigned)(iy - loy) < 9u) &&
              ((unsigned)(iz - loz) < 9u);
    unsigned long long m = __ballot(in);
    if (m){
      int mb = __builtin_amdgcn_mbcnt_hi((unsigned)(m >> 32),
               __builtin_amdgcn_mbcnt_lo((unsigned)m, 0));
      if (in && (n + mb) < LCAP) L[n + mb] = (unsigned short)i;
      n += (int)__popcll(m);
    }
  }
  if (lane == 0) cnt[c] = (n <= LCAP) ? n : 0;
}

// ---------------------------------------------------------------------------
// Kernel 1: exact 16-NN + activation staging. R10 (all bit-exact):
//  (a) truncated 20-round tau select,
//  (b) one dwordx4 list load per lane (j = lane*8 + s candidate mapping —
//      same SET, so selects are unchanged),
//  (c) tail gather via LDS winner table instead of 32 ds_bpermutes.
// ---------------------------------------------------------------------------
__global__ __launch_bounds__(512, 6) void knn_kernel(const int* indices,
    const float* qpts, const float4* cpos4, const unsigned short* list,
    const int* cnt, const float* codes, const float* xyzdir,
    half_t* Ain, half_t* Din){
  __shared__ float4 lp[N_C];        // 32 KB
  __shared__ int    sl[8*SLCAP];    // 4 KB
  int tid = threadIdx.x;
  int lane = tid & 63, wave = tid >> 6;
  const float* cc = codes + (size_t)indices[0] * N_C * CDIM;

  for (int c = tid; c < N_C; c += 512) lp[c] = cpos4[c];
  __syncthreads();

  int q = blockIdx.x * 8 + wave;
  float qx = qpts[q*3 + 0];
  float qy = qpts[q*3 + 1];
  float qz = qpts[q*3 + 2];
  float nqx = -2.0f*qx, nqy = -2.0f*qy, nqz = -2.0f*qz;
  float qq = fmaf(qx, qx, fmaf(qy, qy, qz*qz));   // |q|^2

  int cx = min((int)(qx * 16.0f), 15);
  int cy = min((int)(qy * 16.0f), 15);
  int cz = min((int)(qz * 16.0f), 15);
  int cell = cx | (cy << 4) | (cz << 8);
  int lox = min(max(cx - 4, 0), 7);
  int loy = min(max(cy - 4, 0), 7);
  int loz = min(max(cz - 4, 0), 7);
  int nl = cnt[cell];

  // One 16B load: this lane's 8 candidate indices.
  u16x8 cand8 = *(const u16x8*)(list + (size_t)cell * LSTORE + lane * 8);

  int p[NSLOT];
  int lanemin = KINF;
#pragma unroll
  for (int s = 0; s < NSLOT; s++){
    int j = lane*8 + s;
    int idx = (int)cand8[s] & 2047;   // mask stale pad -> safe LDS read
    float4 P = lp[idx];
    float sc = fmaf(P.x, nqx, fmaf(P.y, nqy, fmaf(P.z, nqz, P.w)));
    int pv = (__float_as_int(sc) & 0xFFFFF800) | idx;
    pv = (j < nl) ? pv : KINF;
    asm("" : "+v"(pv));
    p[s] = pv;
    lanemin = min(lanemin, pv);
  }

  // tau: truncated-exact threshold (>= 16 candidates pass, guaranteed).
  int tau = select16_tau(lanemin);

  int* slw = &sl[wave * SLCAP];
  int n = 0;
#pragma unroll
  for (int s = 0; s < NSLOT; s++){
    bool c = (p[s] <= tau);
    unsigned long long m = __ballot(c);
    if (m){
      if (n <= 64){
        if (c){
          int mb = __builtin_amdgcn_mbcnt_hi((unsigned)(m >> 32),
                   __builtin_amdgcn_mbcnt_lo((unsigned)m, 0));
          slw[n + mb] = p[s];
        }
      }
      n += (int)__popcll(m);
    }
  }
  __builtin_amdgcn_wave_barrier();

  int keep = KINF;
  bool need_fb = true;
  if (n >= KNN_K && n <= 64){
    int x = (lane < n) ? slw[lane] : KINF;
    int P2 = select16th(x);           // exact 16th smallest candidate
    unsigned long long wmask = __ballot(x <= P2);
    int pos = __builtin_amdgcn_mbcnt_hi((unsigned)(wmask >> 32),
              __builtin_amdgcn_mbcnt_lo((unsigned)wmask, 0));
    if (x <= P2) slw[pos] = x;        // exactly 16 winners -> slots 0..15
    __builtin_amdgcn_wave_barrier();
    keep = (lane < KNN_K) ? slw[lane] : KINF;

    // Certificate: d^2 = s - 4 + |q|^2 (truncation < 2^-10) vs clearance^2.
    float d2u = __int_as_float(P2 & 0xFFFFF800) - 4.0f + qq + 0.002f;
    float lofx = lox * 0.0625f, lofy = loy * 0.0625f, lofz = loz * 0.0625f;
    float cl = 1e9f;
    if (lox > 0) cl = fminf(cl, qx - lofx);
    if (lox < 7) cl = fminf(cl, lofx + 0.5625f - qx);
    if (loy > 0) cl = fminf(cl, qy - lofy);
    if (loy < 7) cl = fminf(cl, lofy + 0.5625f - qy);
    if (loz > 0) cl = fminf(cl, qz - lofz);
    if (loz < 7) cl = fminf(cl, lofz + 0.5625f - qz);
    need_fb = !(d2u <= cl * cl);
  }
  if (need_fb) keep = knn_fallback(lp, nqx, nqy, nqz, lane);

  int ci = keep & 0x7FF;
  float4 P = lp[ci];
  float dx = qx - P.x, dy = qy - P.y, dz = qz - P.z;
  float d2 = fmaf(dz, dz, fmaf(dy, dy, dx*dx));
  float w = 1.0f / (d2 + 1e-16f);
  float wm = (lane < KNN_K) ? w : 0.0f;
  wm += dppxf(wm, 1);
  wm += dppxf(wm, 2);
  wm += __shfl_xor(wm, 4, 64);
  wm += dppxf(wm, 8);
  float wn = w / wm;

  // R10: winner table in LDS (broadcast reads) replaces 32 ds_bpermutes.
  if (lane < KNN_K){
    slw[64 + 2*lane]     = ci;
    slw[64 + 2*lane + 1] = __float_as_int(wn);
  }
  __builtin_amdgcn_wave_barrier();

  float acc = 0.f;
#pragma unroll
  for (int i = 0; i < KNN_K; i++){
    int   cb = slw[64 + 2*i];
    float wb = __int_as_float(slw[64 + 2*i + 1]);
    acc = fmaf(wb, cc[cb*CDIM + lane], acc);
  }
  size_t arow = (size_t)q * ASTRIDE;
  Ain[arow + lane] = (half_t)acc;

  float xv = (lane < 63) ? xyzdir[(size_t)q*90 + lane] : 0.f;
  Ain[arow + 64 + lane] = (half_t)xv;
  if (lane < 8) Ain[arow + 128 + lane] = (half_t)0.f;
  if (lane < 40){
    float dv = (lane < 27) ? xyzdir[(size_t)q*90 + 63 + lane] : 0.f;
    Din[(size_t)q*DSTRIDE + lane] = (half_t)dv;
  }
}

// ---------------------------------------------------------------------------
// Kernel 2: fused MFMA MLP, 64 queries/block — R2 known-good version, frozen.
// ---------------------------------------------------------------------------
template<int NCH, int NT>
__device__ inline void mfma_pl(const half_t* act, int astride, int rowbase,
                               const half_t* wlayer, int nt, int ktbase,
                               int tcolbase, v4f acc[2][NT], int lane){
  v8h breg[NCH*NT];
#pragma unroll
  for (int c = 0; c < NCH; c++){
#pragma unroll
    for (int t = 0; t < NT; t++){
      const half_t* bp = wlayer +
          ((size_t)(((ktbase + c)*nt + tcolbase + t) << 9) + (lane << 3));
      breg[c*NT + t] = *(const v8h*)bp;
    }
  }
  int m = lane & 15, quad = lane >> 4;
#pragma unroll
  for (int c = 0; c < NCH; c++){
    v8h a0 = *(const v8h*)&act[(rowbase + m)*astride + c*32 + quad*8];
    v8h a1 = *(const v8h*)&act[(rowbase + 16 + m)*astride + c*32 + quad*8];
#pragma unroll
    for (int t = 0; t < NT; t++){
      acc[0][t] = __builtin_amdgcn_mfma_f32_16x16x32_f16(a0, breg[c*NT + t], acc[0][t], 0, 0, 0);
      acc[1][t] = __builtin_amdgcn_mfma_f32_16x16x32_f16(a1, breg[c*NT + t], acc[1][t], 0, 0, 0);
    }
  }
}

template<int NT>
__device__ inline void epilogue64(v4f acc[2][NT], half_t* outb, int rowbase,
                                  int colbase, const float* bias, bool relu,
                                  int lane){
  int n = lane & 15, quad = lane >> 4;
#pragma unroll
  for (int t = 0; t < NT; t++){
    int col = colbase + t*16 + n;
    float bv = bias[col];
#pragma unroll
    for (int g = 0; g < 2; g++){
#pragma unroll
      for (int r = 0; r < 4; r++){
        float v = acc[g][t][r] + bv;
        if (relu) v = fmaxf(v, 0.f);
        outb[(rowbase + g*16 + quad*4 + r)*ASTRIDE + col] = (half_t)v;
      }
    }
  }
}

__global__ __launch_bounds__(512, 6) void mlp_mfma(
    const half_t* Ain, const half_t* Din, const half_t* wt,
    const float* b0, const float* b1, const float* b2, const float* b3,
    const float* bfb, const float* bdb,
    const float* Wsb, const float* bsb, const float* Wrb, const float* brb,
    float* out){
  __shared__ __align__(16) half_t Abuf[64*ASTRIDE];
  __shared__ __align__(16) half_t Pbuf[64*ASTRIDE];
  __shared__ __align__(16) half_t Qbuf[64*ASTRIDE];

  int tid = threadIdx.x, lane = tid & 63, wave = tid >> 6;
  int qbase = blockIdx.x * 64;

  for (int i = tid; i < 64*17; i += 512){
    int r = i / 17, c8 = i - r*17;
    *(uint4*)&Abuf[r*ASTRIDE + (c8 << 3)] =
        *(const uint4*)&Ain[(size_t)(qbase + r)*ASTRIDE + (c8 << 3)];
  }
  __syncthreads();

  int rowbase  = (wave >> 2) * 32;
  int colq     = wave & 3;
  int colbase  = colq * 32;
  int tcolbase = colq * 2;
  v4f acc[2][2];
  v4f accd[2][1];

  const half_t* wt0 = wt;
  const half_t* wt1 = wt + 16384;
  const half_t* wt2 = wt + 32768;
  const half_t* wt3 = wt + 65536;
  const half_t* wtf = wt + 81920;
  const half_t* wtd = wt + 98304;

#define ZACC22() { for (int g_ = 0; g_ < 2; g_++) for (int t_ = 0; t_ < 2; t_++) \
                   for (int e_ = 0; e_ < 4; e_++) acc[g_][t_][e_] = 0.f; }

  // L0: A @ W0 -> P (relu)
  ZACC22();
  mfma_pl<4,2>(Abuf, ASTRIDE, rowbase, wt0, 8, 0, tcolbase, acc, lane);
  epilogue64<2>(acc, Pbuf, rowbase, colbase, b0, true, lane);
  __syncthreads();

  // L1: P @ W1 -> Q (relu)
  ZACC22();
  mfma_pl<4,2>(Pbuf, ASTRIDE, rowbase, wt1, 8, 0, tcolbase, acc, lane);
  epilogue64<2>(acc, Qbuf, rowbase, colbase, b1, true, lane);
  __syncthreads();

  // L2: [input_xyz | h1] @ W2 -> P (relu)   (K = 256)
  ZACC22();
  mfma_pl<4,2>(Abuf, ASTRIDE, rowbase, wt2, 8, 0, tcolbase, acc, lane);
  mfma_pl<4,2>(Qbuf, ASTRIDE, rowbase, wt2, 8, 4, tcolbase, acc, lane);
  epilogue64<2>(acc, Pbuf, rowbase, colbase, b2, true, lane);
  __syncthreads();

  // L3: P @ W3 -> A (h3, kept for sigma; input_xyz dead)
  ZACC22();
  mfma_pl<4,2>(Pbuf, ASTRIDE, rowbase, wt3, 8, 0, tcolbase, acc, lane);
  epilogue64<2>(acc, Abuf, rowbase, colbase, b3, true, lane);
  __syncthreads();

  // Wf: A(h3) @ Wf -> P (no relu)
  ZACC22();
  mfma_pl<4,2>(Abuf, ASTRIDE, rowbase, wtf, 8, 0, tcolbase, acc, lane);
  epilogue64<2>(acc, Pbuf, rowbase, colbase, bfb, false, lane);
  __syncthreads();

  // Wd: [P(final) | Din(dir, straight from global/L2)] @ Wd -> Q[:,0:64]
#pragma unroll
  for (int g_ = 0; g_ < 2; g_++)
#pragma unroll
    for (int e_ = 0; e_ < 4; e_++) accd[g_][0][e_] = 0.f;
  mfma_pl<4,1>(Pbuf, ASTRIDE, rowbase, wtd, 4, 0, colq, accd, lane);
  mfma_pl<1,1>(Din + (size_t)qbase*DSTRIDE, DSTRIDE, rowbase, wtd, 4, 4, colq,
               accd, lane);
  epilogue64<1>(accd, Qbuf, rowbase, colq * 16, bdb, true, lane);
  __syncthreads();

  // Tail: sigma = h3(Abuf).Ws + bs ; rgb = d(Qbuf).Wr + br  (8 thr/query)
  {
    int q = tid >> 3, part = tid & 7;
    float s = 0.f;
#pragma unroll
    for (int k = 0; k < 16; k++){
      int kk = part*16 + k;
      s = fmaf((float)Abuf[q*ASTRIDE + kk], Wsb[kk], s);
    }
    s += __shfl_xor(s, 1, 64); s += __shfl_xor(s, 2, 64); s += __shfl_xor(s, 4, 64);

    float r3[3];
#pragma unroll
    for (int c2 = 0; c2 < 3; c2++){
      float rv = 0.f;
#pragma unroll
      for (int k = 0; k < 8; k++){
        int kk = part*8 + k;
        rv = fmaf((float)Qbuf[q*ASTRIDE + kk], Wrb[kk*3 + c2], rv);
      }
      rv += __shfl_xor(rv, 1, 64); rv += __shfl_xor(rv, 2, 64); rv += __shfl_xor(rv, 4, 64);
      r3[c2] = rv;
    }
    if (part == 0){
      size_t ob = ((size_t)(qbase + q)) * 4;
      out[ob + 0] = r3[0] + brb[0];
      out[ob + 1] = r3[1] + brb[1];
      out[ob + 2] = r3[2] + brb[2];
      out[ob + 3] = s + bsb[0];
    }
  }
}

// ---------------------------------------------------------------------------
extern "C" void kernel_launch(void* const* d_in, const int* in_sizes, int n_in,
                              void* d_out, int out_size, void* d_ws, size_t ws_size,
                              hipStream_t stream){
  (void)in_sizes; (void)n_in; (void)out_size; (void)ws_size;

  const int*   indices = (const int*)d_in[0];
  const float* qpts    = (const float*)d_in[1];
  const float* xyzdir  = (const float*)d_in[2];
  const float* cpos    = (const float*)d_in[3];
  const float* codes   = (const float*)d_in[4];
  const float* W0 = (const float*)d_in[5];
  const float* b0 = (const float*)d_in[6];
  const float* W1 = (const float*)d_in[7];
  const float* b1 = (const float*)d_in[8];
  const float* W2 = (const float*)d_in[9];
  const float* b2 = (const float*)d_in[10];
  const float* W3 = (const float*)d_in[11];
  const float* b3 = (const float*)d_in[12];
  const float* Wf = (const float*)d_in[13];
  const float* bf = (const float*)d_in[14];
  const float* Wd = (const float*)d_in[15];
  const float* bd = (const float*)d_in[16];
  const float* Ws = (const float*)d_in[17];
  const float* bs = (const float*)d_in[18];
  const float* Wr = (const float*)d_in[19];
  const float* br = (const float*)d_in[20];

  // ws layout (16-B aligned): Ain | Din | wt | cpos4 | list | cnt
  half_t* Ain            = (half_t*)d_ws;                          // 17,825,792
  half_t* Din            = (half_t*)((char*)d_ws + 17825792);      //  5,242,880
  half_t* wt             = (half_t*)((char*)d_ws + 23068672);      //    217,088
  float4* cpos4          = (float4*)((char*)d_ws + 23285760);      //     32,768
  unsigned short* list   = (unsigned short*)((char*)d_ws + 23318528); // 4,194,304
  int* cnt               = (int*)((char*)d_ws + 27512832);         //     16,384

  wtrans_kernel<<<(110592 + 255)/256, 256, 0, stream>>>(W0, W1, W2, W3, Wf, Wd,
                                                        indices, cpos, wt, cpos4);
  grid_kernel<<<GCELLS/8, 512, 0, stream>>>(cpos4, list, cnt);
  knn_kernel<<<N_Q/8, 512, 0, stream>>>(indices, qpts, cpos4, list, cnt,
                                        codes, xyzdir, Ain, Din);
  mlp_mfma<<<N_Q/64, 512, 0, stream>>>(Ain, Din, wt,
                                       b0, b1, b2, b3, bf, bd, Ws, bs, Wr, br,
                                       (float*)d_out);
}

// Round 11
// 199.715 us; speedup vs baseline: 3.5384x; 1.0095x over previous
//
#include <hip/hip_runtime.h>

#define N_Q   65536
#define N_C   2048
#define KNN_K 16
#define CDIM  64
#define SLCAP 128
#define KINF  0x7FFFFFFF
#define WSZ   108544  // halves per weight image

#define GN     16     // grid cells per axis
#define GCELLS 4096
#define LCAP   448    // per-cell candidate capacity (u16)
#define LSTORE 512    // padded storage per cell (u16) for safe dwordx4 reads
#define NSLOT  8      // candidate slots per lane (one 16B load)

typedef _Float16 half_t;
typedef float v4f __attribute__((ext_vector_type(4)));
typedef half_t v8h __attribute__((ext_vector_type(8)));
typedef unsigned short u16x8 __attribute__((ext_vector_type(8)));

#define ASTRIDE 136   // 128 + 8 pad (halves); row = 272 B = 17*16 B
#define DSTRIDE 40    // 32 + 8 pad

// ---------------------------------------------------------------------------
// DPP lane-xor (wm tree reduction).
// ---------------------------------------------------------------------------
__device__ __forceinline__ int dppx(int v, int j){
  if (j == 1) return __builtin_amdgcn_mov_dpp(v, 0xB1,  0xF, 0xF, true);
  if (j == 2) return __builtin_amdgcn_mov_dpp(v, 0x4E,  0xF, 0xF, true);
  if (j == 8) return __builtin_amdgcn_mov_dpp(v, 0x128, 0xF, 0xF, true);
  return __shfl_xor(v, j, 64);
}
__device__ __forceinline__ float dppxf(float v, int j){
  return __int_as_float(dppx(__float_as_int(v), j));
}

__device__ __forceinline__ int mbcnt64(unsigned long long m){
  return __builtin_amdgcn_mbcnt_hi((unsigned)(m >> 32),
         __builtin_amdgcn_mbcnt_lo((unsigned)m, 0));
}

// R11: DUAL selection — two independent binary-search chains interleaved in
// one wave (2x IPC on the dominant serial dependency; per-query semantics
// identical to the R9/R10-proven single versions).
__device__ __forceinline__ void select16_tau2(int xA, int xB, int& tA, int& tB){
  int PA = 0, PB = 0;
#pragma unroll
  for (int b = 30; b >= 11; --b){
    unsigned long long mA = __ballot(xA < (PA | (1 << b)));
    unsigned long long mB = __ballot(xB < (PB | (1 << b)));
    if ((int)__popcll(mA) < 16) PA |= (1 << b);
    if ((int)__popcll(mB) < 16) PB |= (1 << b);
  }
  tA = PA | 0x7FF;
  tB = PB | 0x7FF;
}

__device__ __forceinline__ void select16th2(int xA, int xB, int& QA, int& QB){
  int PA = 0, PB = 0;
#pragma unroll
  for (int b = 30; b >= 0; --b){
    unsigned long long mA = __ballot(xA < (PA | (1 << b)));
    unsigned long long mB = __ballot(xB < (PB | (1 << b)));
    if ((int)__popcll(mA) < 16) PA |= (1 << b);
    if ((int)__popcll(mB) < 16) PB |= (1 << b);
  }
  QA = PA;
  QB = PB;
}

// Rare-path exact 16-NN (full 2048 rescan, register-light).
__device__ __forceinline__ int knn_fallback(const float4* lp, float nqx,
                                            float nqy, float nqz, int lane){
  unsigned used = 0u;
  int keep = KINF;
#pragma unroll 1
  for (int rr = 0; rr < KNN_K; rr++){
    int best = KINF;
#pragma unroll 1
    for (int j = 0; j < 32; j++){
      int c = j*64 + lane;
      float4 P = lp[c];
      float s = fmaf(P.x, nqx, fmaf(P.y, nqy, fmaf(P.z, nqz, P.w)));
      int pv = (__float_as_int(s) & 0xFFFFF800) | c;
      pv = ((used >> j) & 1u) ? KINF : pv;
      best = min(best, pv);
    }
    int gm = best;
#pragma unroll
    for (int off2 = 1; off2 < 64; off2 <<= 1)
      gm = min(gm, __shfl_xor(gm, off2, 64));
    if (lane == rr) keep = gm;
    int gc = gm & 0x7FF;
    if ((gc & 63) == lane) used |= (1u << (gc >> 6));
  }
  return keep;
}

// ---------------------------------------------------------------------------
// Kernel 0: weights -> fp16 MFMA-fragment-order tiles + cpos4 (unchanged)
// ---------------------------------------------------------------------------
__global__ void wtrans_kernel(const float* W0, const float* W1, const float* W2,
                              const float* W3, const float* Wf, const float* Wd,
                              const int* indices, const float* cpos,
                              half_t* wt, float4* cpos4){
  int idx = blockIdx.x * 256 + threadIdx.x;
  if (idx >= 110592) return;
  if (idx >= WSZ){
    int i = idx - WSZ;
    const float* cp = cpos + (size_t)indices[0] * N_C * 3;
    float x = cp[i*3 + 0], y = cp[i*3 + 1], z = cp[i*3 + 2];
    cpos4[i] = make_float4(x, y, z, fmaf(x, x, fmaf(y, y, fmaf(z, z, 4.0f))));
    return;
  }
  int base, nt, mode;            // mode: 0 plain(src), 1 W0, 2 W2, 3 Wd
  const float* src = W1;
  if (idx < 16384){ base = 0; nt = 8; mode = 1; }
  else if (idx < 32768){ base = 16384; nt = 8; mode = 0; src = W1; }
  else if (idx < 65536){ base = 32768; nt = 8; mode = 2; }
  else if (idx < 81920){ base = 65536; nt = 8; mode = 0; src = W3; }
  else if (idx < 98304){ base = 81920; nt = 8; mode = 0; src = Wf; }
  else { base = 98304; nt = 4; mode = 3; }
  int i = idx - base;
  int tile = i >> 9, e = i & 511;
  int lane = e >> 3, j = e & 7;
  int k0idx = tile / nt, tcol = tile - k0idx*nt;
  int n = tcol*16 + (lane & 15);
  int k = k0idx*32 + ((lane >> 4) << 3) + j;
  float val;
  if (mode == 0)      val = src[k*128 + n];
  else if (mode == 1) val = (k < 127) ? W0[k*128 + n] : 0.f;
  else if (mode == 2) val = (k == 127) ? 0.f
                           : ((k < 127) ? W2[k*128 + n] : W2[(k-1)*128 + n]);
  else                val = (k < 155) ? Wd[k*64 + n] : 0.f;
  wt[idx] = (half_t)val;
}

// ---------------------------------------------------------------------------
// Kernel 0.5: per-cell candidate lists, 9-cell window (unchanged from R10).
// ---------------------------------------------------------------------------
__global__ __launch_bounds__(512) void grid_kernel(const float4* cpos4,
    unsigned short* list, int* cnt){
  int lane = threadIdx.x & 63, wave = threadIdx.x >> 6;
  int c = blockIdx.x * 8 + wave;
  int cx = c & 15, cy = (c >> 4) & 15, cz = c >> 8;
  int lox = min(max(cx - 4, 0), 7);
  int loy = min(max(cy - 4, 0), 7);
  int loz = min(max(cz - 4, 0), 7);
  unsigned short* L = list + (size_t)c * LSTORE;
  int n = 0;
#pragma unroll 1
  for (int b = 0; b < 32; b++){
    int i = b * 64 + lane;
    float4 P = cpos4[i];
    int ix = min((int)(P.x * 16.0f), 15);
    int iy = min((int)(P.y * 16.0f), 15);
    int iz = min((int)(P.z * 16.0f), 15);
    bool in = ((unsigned)(ix - lox) < 9u) && ((unsigned)(iy - loy) < 9u) &&
              ((unsigned)(iz - loz) < 9u);
    unsigned long long m = __ballot(in);
    if (m){
      int mb = mbcnt64(m);
      if (in && (n + mb) < LCAP) L[n + mb] = (unsigned short)i;
      n += (int)__popcll(m);
    }
  }
  if (lane == 0) cnt[c] = (n <= LCAP) ? n : 0;
}

// ---------------------------------------------------------------------------
// Kernel 1: exact 16-NN + activation staging. R11: TWO queries per wave,
// fully interleaved dual state. Per-query algorithm identical to R10
// (bit-exact); the two independent select chains + gather loops interleave
// for ~2x IPC on the serial sections, and lp staging amortizes over 16
// queries/block instead of 8.
// ---------------------------------------------------------------------------
__global__ __launch_bounds__(512, 6) void knn_kernel(const int* indices,
    const float* qpts, const float4* cpos4, const unsigned short* list,
    const int* cnt, const float* codes, const float* xyzdir,
    half_t* Ain, half_t* Din){
  __shared__ float4 lp[N_C];         // 32 KB
  __shared__ int    sl[16*SLCAP];    // 8 KB (2 slots per wave)
  int tid = threadIdx.x;
  int lane = tid & 63, wave = tid >> 6;
  const float* cc = codes + (size_t)indices[0] * N_C * CDIM;

  for (int c = tid; c < N_C; c += 512) lp[c] = cpos4[c];
  __syncthreads();

  int qA = blockIdx.x * 16 + wave * 2;
  int qB = qA + 1;
  float qxA = qpts[qA*3 + 0], qyA = qpts[qA*3 + 1], qzA = qpts[qA*3 + 2];
  float qxB = qpts[qB*3 + 0], qyB = qpts[qB*3 + 1], qzB = qpts[qB*3 + 2];
  float nqxA = -2.0f*qxA, nqyA = -2.0f*qyA, nqzA = -2.0f*qzA;
  float nqxB = -2.0f*qxB, nqyB = -2.0f*qyB, nqzB = -2.0f*qzB;
  float qqA = fmaf(qxA, qxA, fmaf(qyA, qyA, qzA*qzA));
  float qqB = fmaf(qxB, qxB, fmaf(qyB, qyB, qzB*qzB));

  int cxA = min((int)(qxA * 16.0f), 15);
  int cyA = min((int)(qyA * 16.0f), 15);
  int czA = min((int)(qzA * 16.0f), 15);
  int cxB = min((int)(qxB * 16.0f), 15);
  int cyB = min((int)(qyB * 16.0f), 15);
  int czB = min((int)(qzB * 16.0f), 15);
  int cellA = cxA | (cyA << 4) | (czA << 8);
  int cellB = cxB | (cyB << 4) | (czB << 8);
  int loxA = min(max(cxA - 4, 0), 7), loyA = min(max(cyA - 4, 0), 7),
      lozA = min(max(czA - 4, 0), 7);
  int loxB = min(max(cxB - 4, 0), 7), loyB = min(max(cyB - 4, 0), 7),
      lozB = min(max(czB - 4, 0), 7);
  int nlA = cnt[cellA];
  int nlB = cnt[cellB];

  u16x8 c8A = *(const u16x8*)(list + (size_t)cellA * LSTORE + lane * 8);
  u16x8 c8B = *(const u16x8*)(list + (size_t)cellB * LSTORE + lane * 8);

  int pA[NSLOT], pB[NSLOT];
  int lmA = KINF, lmB = KINF;
#pragma unroll
  for (int s = 0; s < NSLOT; s++){
    int j = lane*8 + s;
    int iA = (int)c8A[s] & 2047;
    int iB = (int)c8B[s] & 2047;
    float4 PA = lp[iA];
    float4 PB = lp[iB];
    float sA = fmaf(PA.x, nqxA, fmaf(PA.y, nqyA, fmaf(PA.z, nqzA, PA.w)));
    float sB = fmaf(PB.x, nqxB, fmaf(PB.y, nqyB, fmaf(PB.z, nqzB, PB.w)));
    int pvA = (__float_as_int(sA) & 0xFFFFF800) | iA;
    int pvB = (__float_as_int(sB) & 0xFFFFF800) | iB;
    pvA = (j < nlA) ? pvA : KINF;
    pvB = (j < nlB) ? pvB : KINF;
    asm("" : "+v"(pvA));
    asm("" : "+v"(pvB));
    pA[s] = pvA; pB[s] = pvB;
    lmA = min(lmA, pvA);
    lmB = min(lmB, pvB);
  }

  int tauA, tauB;
  select16_tau2(lmA, lmB, tauA, tauB);

  int* slwA = &sl[(wave*2 + 0) * SLCAP];
  int* slwB = &sl[(wave*2 + 1) * SLCAP];
  int nA = 0, nB = 0;
#pragma unroll
  for (int s = 0; s < NSLOT; s++){
    bool cA = (pA[s] <= tauA);
    bool cB = (pB[s] <= tauB);
    unsigned long long mA = __ballot(cA);
    unsigned long long mB = __ballot(cB);
    int mbA = mbcnt64(mA);
    int mbB = mbcnt64(mB);
    if (cA && nA <= 64) slwA[nA + mbA] = pA[s];
    if (cB && nB <= 64) slwB[nB + mbB] = pB[s];
    nA += (int)__popcll(mA);
    nB += (int)__popcll(mB);
  }
  __builtin_amdgcn_wave_barrier();

  bool okA = (nA >= KNN_K && nA <= 64);
  bool okB = (nB >= KNN_K && nB <= 64);
  int xA = (lane < nA) ? slwA[lane] : KINF;
  int xB = (lane < nB) ? slwB[lane] : KINF;
  int P2A, P2B;
  select16th2(xA, xB, P2A, P2B);
  unsigned long long wmkA = __ballot(xA <= P2A);
  unsigned long long wmkB = __ballot(xB <= P2B);
  int posA = mbcnt64(wmkA);
  int posB = mbcnt64(wmkB);
  if (xA <= P2A) slwA[posA] = xA;
  if (xB <= P2B) slwB[posB] = xB;
  __builtin_amdgcn_wave_barrier();

  int keepA = KINF, keepB = KINF;
  bool fbA = true, fbB = true;
  if (okA){
    keepA = (lane < KNN_K) ? slwA[lane] : KINF;
    float d2u = __int_as_float(P2A & 0xFFFFF800) - 4.0f + qqA + 0.002f;
    float lofx = loxA * 0.0625f, lofy = loyA * 0.0625f, lofz = lozA * 0.0625f;
    float cl = 1e9f;
    if (loxA > 0) cl = fminf(cl, qxA - lofx);
    if (loxA < 7) cl = fminf(cl, lofx + 0.5625f - qxA);
    if (loyA > 0) cl = fminf(cl, qyA - lofy);
    if (loyA < 7) cl = fminf(cl, lofy + 0.5625f - qyA);
    if (lozA > 0) cl = fminf(cl, qzA - lofz);
    if (lozA < 7) cl = fminf(cl, lofz + 0.5625f - qzA);
    fbA = !(d2u <= cl * cl);
  }
  if (okB){
    keepB = (lane < KNN_K) ? slwB[lane] : KINF;
    float d2u = __int_as_float(P2B & 0xFFFFF800) - 4.0f + qqB + 0.002f;
    float lofx = loxB * 0.0625f, lofy = loyB * 0.0625f, lofz = lozB * 0.0625f;
    float cl = 1e9f;
    if (loxB > 0) cl = fminf(cl, qxB - lofx);
    if (loxB < 7) cl = fminf(cl, lofx + 0.5625f - qxB);
    if (loyB > 0) cl = fminf(cl, qyB - lofy);
    if (loyB < 7) cl = fminf(cl, lofy + 0.5625f - qyB);
    if (lozB > 0) cl = fminf(cl, qzB - lofz);
    if (lozB < 7) cl = fminf(cl, lofz + 0.5625f - qzB);
    fbB = !(d2u <= cl * cl);
  }
  if (fbA) keepA = knn_fallback(lp, nqxA, nqyA, nqzA, lane);
  if (fbB) keepB = knn_fallback(lp, nqxB, nqyB, nqzB, lane);

  // Dual tail: weights + winner tables + interleaved gather.
  int ciA = keepA & 0x7FF;
  int ciB = keepB & 0x7FF;
  float4 PA4 = lp[ciA];
  float4 PB4 = lp[ciB];
  float dxA = qxA - PA4.x, dyA = qyA - PA4.y, dzA = qzA - PA4.z;
  float dxB = qxB - PB4.x, dyB = qyB - PB4.y, dzB = qzB - PB4.z;
  float d2A = fmaf(dzA, dzA, fmaf(dyA, dyA, dxA*dxA));
  float d2B = fmaf(dzB, dzB, fmaf(dyB, dyB, dxB*dxB));
  float wA = 1.0f / (d2A + 1e-16f);
  float wB = 1.0f / (d2B + 1e-16f);
  float wmA = (lane < KNN_K) ? wA : 0.0f;
  float wmB = (lane < KNN_K) ? wB : 0.0f;
  wmA += dppxf(wmA, 1);            wmB += dppxf(wmB, 1);
  wmA += dppxf(wmA, 2);            wmB += dppxf(wmB, 2);
  wmA += __shfl_xor(wmA, 4, 64);   wmB += __shfl_xor(wmB, 4, 64);
  wmA += dppxf(wmA, 8);            wmB += dppxf(wmB, 8);
  float wnA = wA / wmA;
  float wnB = wB / wmB;

  if (lane < KNN_K){
    slwA[64 + 2*lane]     = ciA;
    slwA[64 + 2*lane + 1] = __float_as_int(wnA);
    slwB[64 + 2*lane]     = ciB;
    slwB[64 + 2*lane + 1] = __float_as_int(wnB);
  }
  __builtin_amdgcn_wave_barrier();

  float accA = 0.f, accB = 0.f;
#pragma unroll
  for (int i = 0; i < KNN_K; i++){
    int   cbA = slwA[64 + 2*i];
    int   cbB = slwB[64 + 2*i];
    float wbA = __int_as_float(slwA[64 + 2*i + 1]);
    float wbB = __int_as_float(slwB[64 + 2*i + 1]);
    accA = fmaf(wbA, cc[cbA*CDIM + lane], accA);
    accB = fmaf(wbB, cc[cbB*CDIM + lane], accB);
  }
  size_t arowA = (size_t)qA * ASTRIDE;
  size_t arowB = (size_t)qB * ASTRIDE;
  Ain[arowA + lane] = (half_t)accA;
  Ain[arowB + lane] = (half_t)accB;

  float xvA = (lane < 63) ? xyzdir[(size_t)qA*90 + lane] : 0.f;
  float xvB = (lane < 63) ? xyzdir[(size_t)qB*90 + lane] : 0.f;
  Ain[arowA + 64 + lane] = (half_t)xvA;
  Ain[arowB + 64 + lane] = (half_t)xvB;
  if (lane < 8){
    Ain[arowA + 128 + lane] = (half_t)0.f;
    Ain[arowB + 128 + lane] = (half_t)0.f;
  }
  if (lane < 40){
    float dvA = (lane < 27) ? xyzdir[(size_t)qA*90 + 63 + lane] : 0.f;
    float dvB = (lane < 27) ? xyzdir[(size_t)qB*90 + 63 + lane] : 0.f;
    Din[(size_t)qA*DSTRIDE + lane] = (half_t)dvA;
    Din[(size_t)qB*DSTRIDE + lane] = (half_t)dvB;
  }
}

// ---------------------------------------------------------------------------
// Kernel 2: fused MFMA MLP, 64 queries/block — R2 known-good version, frozen.
// ---------------------------------------------------------------------------
template<int NCH, int NT>
__device__ inline void mfma_pl(const half_t* act, int astride, int rowbase,
                               const half_t* wlayer, int nt, int ktbase,
                               int tcolbase, v4f acc[2][NT], int lane){
  v8h breg[NCH*NT];
#pragma unroll
  for (int c = 0; c < NCH; c++){
#pragma unroll
    for (int t = 0; t < NT; t++){
      const half_t* bp = wlayer +
          ((size_t)(((ktbase + c)*nt + tcolbase + t) << 9) + (lane << 3));
      breg[c*NT + t] = *(const v8h*)bp;
    }
  }
  int m = lane & 15, quad = lane >> 4;
#pragma unroll
  for (int c = 0; c < NCH; c++){
    v8h a0 = *(const v8h*)&act[(rowbase + m)*astride + c*32 + quad*8];
    v8h a1 = *(const v8h*)&act[(rowbase + 16 + m)*astride + c*32 + quad*8];
#pragma unroll
    for (int t = 0; t < NT; t++){
      acc[0][t] = __builtin_amdgcn_mfma_f32_16x16x32_f16(a0, breg[c*NT + t], acc[0][t], 0, 0, 0);
      acc[1][t] = __builtin_amdgcn_mfma_f32_16x16x32_f16(a1, breg[c*NT + t], acc[1][t], 0, 0, 0);
    }
  }
}

template<int NT>
__device__ inline void epilogue64(v4f acc[2][NT], half_t* outb, int rowbase,
                                  int colbase, const float* bias, bool relu,
                                  int lane){
  int n = lane & 15, quad = lane >> 4;
#pragma unroll
  for (int t = 0; t < NT; t++){
    int col = colbase + t*16 + n;
    float bv = bias[col];
#pragma unroll
    for (int g = 0; g < 2; g++){
#pragma unroll
      for (int r = 0; r < 4; r++){
        float v = acc[g][t][r] + bv;
        if (relu) v = fmaxf(v, 0.f);
        outb[(rowbase + g*16 + quad*4 + r)*ASTRIDE + col] = (half_t)v;
      }
    }
  }
}

__global__ __launch_bounds__(512, 6) void mlp_mfma(
    const half_t* Ain, const half_t* Din, const half_t* wt,
    const float* b0, const float* b1, const float* b2, const float* b3,
    const float* bfb, const float* bdb,
    const float* Wsb, const float* bsb, const float* Wrb, const float* brb,
    float* out){
  __shared__ __align__(16) half_t Abuf[64*ASTRIDE];
  __shared__ __align__(16) half_t Pbuf[64*ASTRIDE];
  __shared__ __align__(16) half_t Qbuf[64*ASTRIDE];

  int tid = threadIdx.x, lane = tid & 63, wave = tid >> 6;
  int qbase = blockIdx.x * 64;

  for (int i = tid; i < 64*17; i += 512){
    int r = i / 17, c8 = i - r*17;
    *(uint4*)&Abuf[r*ASTRIDE + (c8 << 3)] =
        *(const uint4*)&Ain[(size_t)(qbase + r)*ASTRIDE + (c8 << 3)];
  }
  __syncthreads();

  int rowbase  = (wave >> 2) * 32;
  int colq     = wave & 3;
  int colbase  = colq * 32;
  int tcolbase = colq * 2;
  v4f acc[2][2];
  v4f accd[2][1];

  const half_t* wt0 = wt;
  const half_t* wt1 = wt + 16384;
  const half_t* wt2 = wt + 32768;
  const half_t* wt3 = wt + 65536;
  const half_t* wtf = wt + 81920;
  const half_t* wtd = wt + 98304;

#define ZACC22() { for (int g_ = 0; g_ < 2; g_++) for (int t_ = 0; t_ < 2; t_++) \
                   for (int e_ = 0; e_ < 4; e_++) acc[g_][t_][e_] = 0.f; }

  // L0: A @ W0 -> P (relu)
  ZACC22();
  mfma_pl<4,2>(Abuf, ASTRIDE, rowbase, wt0, 8, 0, tcolbase, acc, lane);
  epilogue64<2>(acc, Pbuf, rowbase, colbase, b0, true, lane);
  __syncthreads();

  // L1: P @ W1 -> Q (relu)
  ZACC22();
  mfma_pl<4,2>(Pbuf, ASTRIDE, rowbase, wt1, 8, 0, tcolbase, acc, lane);
  epilogue64<2>(acc, Qbuf, rowbase, colbase, b1, true, lane);
  __syncthreads();

  // L2: [input_xyz | h1] @ W2 -> P (relu)   (K = 256)
  ZACC22();
  mfma_pl<4,2>(Abuf, ASTRIDE, rowbase, wt2, 8, 0, tcolbase, acc, lane);
  mfma_pl<4,2>(Qbuf, ASTRIDE, rowbase, wt2, 8, 4, tcolbase, acc, lane);
  epilogue64<2>(acc, Pbuf, rowbase, colbase, b2, true, lane);
  __syncthreads();

  // L3: P @ W3 -> A (h3, kept for sigma; input_xyz dead)
  ZACC22();
  mfma_pl<4,2>(Pbuf, ASTRIDE, rowbase, wt3, 8, 0, tcolbase, acc, lane);
  epilogue64<2>(acc, Abuf, rowbase, colbase, b3, true, lane);
  __syncthreads();

  // Wf: A(h3) @ Wf -> P (no relu)
  ZACC22();
  mfma_pl<4,2>(Abuf, ASTRIDE, rowbase, wtf, 8, 0, tcolbase, acc, lane);
  epilogue64<2>(acc, Pbuf, rowbase, colbase, bfb, false, lane);
  __syncthreads();

  // Wd: [P(final) | Din(dir, straight from global/L2)] @ Wd -> Q[:,0:64]
#pragma unroll
  for (int g_ = 0; g_ < 2; g_++)
#pragma unroll
    for (int e_ = 0; e_ < 4; e_++) accd[g_][0][e_] = 0.f;
  mfma_pl<4,1>(Pbuf, ASTRIDE, rowbase, wtd, 4, 0, colq, accd, lane);
  mfma_pl<1,1>(Din + (size_t)qbase*DSTRIDE, DSTRIDE, rowbase, wtd, 4, 4, colq,
               accd, lane);
  epilogue64<1>(accd, Qbuf, rowbase, colq * 16, bdb, true, lane);
  __syncthreads();

  // Tail: sigma = h3(Abuf).Ws + bs ; rgb = d(Qbuf).Wr + br  (8 thr/query)
  {
    int q = tid >> 3, part = tid & 7;
    float s = 0.f;
#pragma unroll
    for (int k = 0; k < 16; k++){
      int kk = part*16 + k;
      s = fmaf((float)Abuf[q*ASTRIDE + kk], Wsb[kk], s);
    }
    s += __shfl_xor(s, 1, 64); s += __shfl_xor(s, 2, 64); s += __shfl_xor(s, 4, 64);

    float r3[3];
#pragma unroll
    for (int c2 = 0; c2 < 3; c2++){
      float rv = 0.f;
#pragma unroll
      for (int k = 0; k < 8; k++){
        int kk = part*8 + k;
        rv = fmaf((float)Qbuf[q*ASTRIDE + kk], Wrb[kk*3 + c2], rv);
      }
      rv += __shfl_xor(rv, 1, 64); rv += __shfl_xor(rv, 2, 64); rv += __shfl_xor(rv, 4, 64);
      r3[c2] = rv;
    }
    if (part == 0){
      size_t ob = ((size_t)(qbase + q)) * 4;
      out[ob + 0] = r3[0] + brb[0];
      out[ob + 1] = r3[1] + brb[1];
      out[ob + 2] = r3[2] + brb[2];
      out[ob + 3] = s + bsb[0];
    }
  }
}

// ---------------------------------------------------------------------------
extern "C" void kernel_launch(void* const* d_in, const int* in_sizes, int n_in,
                              void* d_out, int out_size, void* d_ws, size_t ws_size,
                              hipStream_t stream){
  (void)in_sizes; (void)n_in; (void)out_size; (void)ws_size;

  const int*   indices = (const int*)d_in[0];
  const float* qpts    = (const float*)d_in[1];
  const float* xyzdir  = (const float*)d_in[2];
  const float* cpos    = (const float*)d_in[3];
  const float* codes   = (const float*)d_in[4];
  const float* W0 = (const float*)d_in[5];
  const float* b0 = (const float*)d_in[6];
  const float* W1 = (const float*)d_in[7];
  const float* b1 = (const float*)d_in[8];
  const float* W2 = (const float*)d_in[9];
  const float* b2 = (const float*)d_in[10];
  const float* W3 = (const float*)d_in[11];
  const float* b3 = (const float*)d_in[12];
  const float* Wf = (const float*)d_in[13];
  const float* bf = (const float*)d_in[14];
  const float* Wd = (const float*)d_in[15];
  const float* bd = (const float*)d_in[16];
  const float* Ws = (const float*)d_in[17];
  const float* bs = (const float*)d_in[18];
  const float* Wr = (const float*)d_in[19];
  const float* br = (const float*)d_in[20];

  // ws layout (16-B aligned): Ain | Din | wt | cpos4 | list | cnt
  half_t* Ain            = (half_t*)d_ws;                          // 17,825,792
  half_t* Din            = (half_t*)((char*)d_ws + 17825792);      //  5,242,880
  half_t* wt             = (half_t*)((char*)d_ws + 23068672);      //    217,088
  float4* cpos4          = (float4*)((char*)d_ws + 23285760);      //     32,768
  unsigned short* list   = (unsigned short*)((char*)d_ws + 23318528); // 4,194,304
  int* cnt               = (int*)((char*)d_ws + 27512832);         //     16,384

  wtrans_kernel<<<(110592 + 255)/256, 256, 0, stream>>>(W0, W1, W2, W3, Wf, Wd,
                                                        indices, cpos, wt, cpos4);
  grid_kernel<<<GCELLS/8, 512, 0, stream>>>(cpos4, list, cnt);
  knn_kernel<<<N_Q/16, 512, 0, stream>>>(indices, qpts, cpos4, list, cnt,
                                         codes, xyzdir, Ain, Din);
  mlp_mfma<<<N_Q/64, 512, 0, stream>>>(Ain, Din, wt,
                                       b0, b1, b2, b3, bf, bd, Ws, bs, Wr, br,
                                       (float*)d_out);
}